// Round 1
// baseline (1162.161 us; speedup 1.0000x reference)
//
#include <hip/hip_runtime.h>

#define DIM   256
#define NE    8192
#define NTOK  16384

// d_out flat offsets (floats)
#define OFF_Q    0
#define OFF_DIFF 4194304
#define OFF_IND  4194305
#define OFF_OH   4210689
#define OFF_ES   4218881

// dist GEMM tiling
#define BM 128
#define BN 128
#define BK 32
#define SPLITS 4
#define CODES_PER_SPLIT (NE / SPLITS)    // 2048
#define NB_ITERS (CODES_PER_SPLIT / BN)  // 16
#define KB_ITERS (DIM / BK)              // 8
#define XS_STRIDE 132                    // 128 + 4 pad, keeps 16B alignment
#define BS_STRIDE 132

// ---------------------------------------------------------------------------
// e2[k] = sum_d embed[d][k]^2
__global__ void e2_kernel(const float* __restrict__ embed, float* __restrict__ e2) {
    int c = blockIdx.x * 256 + threadIdx.x;
    float s = 0.f;
    for (int d = 0; d < DIM; ++d) {
        float v = embed[(size_t)d * NE + c];
        s = fmaf(v, v, s);
    }
    e2[c] = s;
}

// ---------------------------------------------------------------------------
// embedT[k][d] = embed[d][k]  (for coalesced gather later)
__global__ void transpose_kernel(const float* __restrict__ embed, float* __restrict__ embedT) {
    __shared__ __align__(16) float t2[64][DIM + 4];
    int c0 = blockIdx.x * 64;
    int tid = threadIdx.x;
    for (int t = 0; t < 64; ++t) {
        int i = tid + t * 256;
        int dd = i >> 6, cc = i & 63;
        t2[cc][dd] = embed[(size_t)dd * NE + c0 + cc];
    }
    __syncthreads();
    for (int t = 0; t < 16; ++t) {
        int i = tid + t * 256;      // float4 units, 0..4095
        int cc = i >> 6, dq = i & 63;
        float4 v = *(const float4*)&t2[cc][dq * 4];
        *(float4*)&embedT[(size_t)(c0 + cc) * DIM + dq * 4] = v;
    }
}

// ---------------------------------------------------------------------------
// Fused dist + row-argmin. dist = e2[k] - 2 * (x . e_k)  (x^2 added later;
// constant per row so argmin-invariant). Each block: 128 tokens x 2048 codes.
__global__ __launch_bounds__(256, 2) void dist_argmin_kernel(
    const float* __restrict__ x, const float* __restrict__ embed,
    const float* __restrict__ e2,
    float* __restrict__ candv, int* __restrict__ candi) {
    __shared__ __align__(16) float xs[BK][XS_STRIDE];
    __shared__ __align__(16) float bs[BK][BS_STRIDE];
    __shared__ float es[BN];

    const int tid = threadIdx.x;
    const int tx = tid & 15;        // code dimension (16 threads)
    const int ty = tid >> 4;        // token dimension (16 threads)
    const int split = blockIdx.x;   // 0..3, codes split*2048 ..
    const int m0 = blockIdx.y * BM;

    float bestv[8];
    int   besti[8];
#pragma unroll
    for (int i = 0; i < 8; ++i) { bestv[i] = 3.4e38f; besti[i] = 0x7fffffff; }

    for (int nb = 0; nb < NB_ITERS; ++nb) {
        const int n0 = split * CODES_PER_SPLIT + nb * BN;
        float acc[8][8];
#pragma unroll
        for (int i = 0; i < 8; ++i)
#pragma unroll
            for (int j = 0; j < 8; ++j) acc[i][j] = 0.f;

        for (int kb = 0; kb < KB_ITERS; ++kb) {
            const int k0 = kb * BK;
            __syncthreads();
            // stage x tile transposed: xs[k][m], 128 m x 32 k
#pragma unroll
            for (int t = 0; t < 4; ++t) {
                int i4 = tid + t * 256;
                int mm = i4 >> 3, kq = i4 & 7;
                float4 v = *(const float4*)&x[(size_t)(m0 + mm) * DIM + k0 + kq * 4];
                xs[kq * 4 + 0][mm] = v.x;
                xs[kq * 4 + 1][mm] = v.y;
                xs[kq * 4 + 2][mm] = v.z;
                xs[kq * 4 + 3][mm] = v.w;
            }
            // stage embed tile natural layout: bs[k][n], 32 k x 128 n
#pragma unroll
            for (int t = 0; t < 4; ++t) {
                int i4 = tid + t * 256;
                int kk = i4 >> 5, nq = i4 & 31;
                float4 v = *(const float4*)&embed[(size_t)(k0 + kk) * NE + n0 + nq * 4];
                *(float4*)&bs[kk][nq * 4] = v;
            }
            if (kb == 0 && tid < BN) es[tid] = e2[n0 + tid];
            __syncthreads();

#pragma unroll 4
            for (int k = 0; k < BK; ++k) {
                float4 a0 = *(const float4*)&xs[k][ty * 8];
                float4 a1 = *(const float4*)&xs[k][ty * 8 + 4];
                float4 b0 = *(const float4*)&bs[k][tx * 8];
                float4 b1 = *(const float4*)&bs[k][tx * 8 + 4];
                float a[8] = {a0.x, a0.y, a0.z, a0.w, a1.x, a1.y, a1.z, a1.w};
                float b[8] = {b0.x, b0.y, b0.z, b0.w, b1.x, b1.y, b1.z, b1.w};
#pragma unroll
                for (int i = 0; i < 8; ++i)
#pragma unroll
                    for (int j = 0; j < 8; ++j)
                        acc[i][j] = fmaf(a[i], b[j], acc[i][j]);
            }
        }
        // running argmin update (codes processed in ascending order; strict <
        // keeps the first occurrence like jnp.argmin)
#pragma unroll
        for (int i = 0; i < 8; ++i) {
#pragma unroll
            for (int j = 0; j < 8; ++j) {
                float v = es[tx * 8 + j] - 2.0f * acc[i][j];
                if (v < bestv[i]) { bestv[i] = v; besti[i] = n0 + tx * 8 + j; }
            }
        }
    }

    // reduce across the 16 tx lanes (same ty, same wave). Tie-break on index.
#pragma unroll
    for (int m = 1; m < 16; m <<= 1) {
#pragma unroll
        for (int i = 0; i < 8; ++i) {
            float ov = __shfl_xor(bestv[i], m);
            int   oi = __shfl_xor(besti[i], m);
            if (ov < bestv[i] || (ov == bestv[i] && oi < besti[i])) {
                bestv[i] = ov; besti[i] = oi;
            }
        }
    }
    if (tx == 0) {
#pragma unroll
        for (int i = 0; i < 8; ++i) {
            int token = m0 + ty * 8 + i;
            candv[(size_t)split * NTOK + token] = bestv[i];
            candi[(size_t)split * NTOK + token] = besti[i];
        }
    }
}

// ---------------------------------------------------------------------------
// Combine the 4 split candidates per token, compute x2, write ind/embed_ind,
// accumulate diff = mean ||quantize - x||^2 via min-dist identity.
__global__ void combine_kernel(const float* __restrict__ x,
                               const float* __restrict__ candv,
                               const int* __restrict__ candi,
                               int* __restrict__ ind, float* __restrict__ out) {
    __shared__ float partial[4];
    int tid = threadIdx.x;
    int w = tid >> 6, lane = tid & 63;
    float dsum = 0.f;
    for (int tt = 0; tt < 16; ++tt) {
        int token = blockIdx.x * 64 + w * 16 + tt;
        float4 xv = *(const float4*)&x[(size_t)token * DIM + lane * 4];
        float x2 = xv.x * xv.x + xv.y * xv.y + xv.z * xv.z + xv.w * xv.w;
#pragma unroll
        for (int m = 1; m < 64; m <<= 1) x2 += __shfl_xor(x2, m);
        if (lane == 0) {
            float bv = candv[token];
            int   bi = candi[token];
            for (int s = 1; s < SPLITS; ++s) {
                float v = candv[(size_t)s * NTOK + token];
                int  i2 = candi[(size_t)s * NTOK + token];
                if (v < bv || (v == bv && i2 < bi)) { bv = v; bi = i2; }
            }
            ind[token] = bi;
            out[OFF_IND + token] = (float)bi;
            dsum += x2 + bv;   // = ||x - e_bi||^2 (up to fp rounding)
        }
    }
    if (lane == 0) partial[w] = dsum;
    __syncthreads();
    if (tid == 0) {
        float t = (partial[0] + partial[1] + partial[2] + partial[3]) *
                  (1.0f / 4194304.0f);
        atomicAdd(&out[OFF_DIFF], t);
    }
}

// ---------------------------------------------------------------------------
// Gather quantize rows, histogram counts, scatter embed_sum.
__global__ void gather_scatter_kernel(const float* __restrict__ x,
                                      const float* __restrict__ embedT,
                                      const float* __restrict__ embed,
                                      const int* __restrict__ ind,
                                      float* __restrict__ out, int useT) {
    int tid = threadIdx.x;
    int w = tid >> 6, lane = tid & 63;
#pragma unroll
    for (int tt = 0; tt < 4; ++tt) {
        int token = blockIdx.x * 16 + w * 4 + tt;
        int k = ind[token];
        float4 q;
        if (useT) {
            q = *(const float4*)&embedT[(size_t)k * DIM + lane * 4];
        } else {
            q.x = embed[(size_t)(lane * 4 + 0) * NE + k];
            q.y = embed[(size_t)(lane * 4 + 1) * NE + k];
            q.z = embed[(size_t)(lane * 4 + 2) * NE + k];
            q.w = embed[(size_t)(lane * 4 + 3) * NE + k];
        }
        *(float4*)&out[OFF_Q + (size_t)token * DIM + lane * 4] = q;
        float4 xv = *(const float4*)&x[(size_t)token * DIM + lane * 4];
        atomicAdd(&out[OFF_ES + (size_t)(lane * 4 + 0) * NE + k], xv.x);
        atomicAdd(&out[OFF_ES + (size_t)(lane * 4 + 1) * NE + k], xv.y);
        atomicAdd(&out[OFF_ES + (size_t)(lane * 4 + 2) * NE + k], xv.z);
        atomicAdd(&out[OFF_ES + (size_t)(lane * 4 + 3) * NE + k], xv.w);
        if (lane == 0) atomicAdd(&out[OFF_OH + k], 1.0f);
    }
}

// ---------------------------------------------------------------------------
extern "C" void kernel_launch(void* const* d_in, const int* in_sizes, int n_in,
                              void* d_out, int out_size, void* d_ws, size_t ws_size,
                              hipStream_t stream) {
    const float* x     = (const float*)d_in[0];
    const float* embed = (const float*)d_in[1];
    float* out = (float*)d_out;
    float* wsf = (float*)d_ws;

    // ws layout: [embedT 2097152][e2 8192][candv 65536][candi 65536][ind 16384]
    const size_t need_full = (size_t)(2097152 + 8192 + 2 * 65536 + 16384) * 4;
    int useT = (ws_size >= need_full) ? 1 : 0;
    float* embedT = wsf;
    float* e2     = useT ? (wsf + 2097152) : wsf;
    float* candv  = e2 + 8192;
    int*   candi  = (int*)(candv + 4 * NTOK);
    int*   ind    = candi + 4 * NTOK;

    // zero accumulator regions (diff .. end; embed_ind gets fully overwritten)
    hipMemsetAsync((char*)d_out + (size_t)OFF_DIFF * 4, 0,
                   ((size_t)out_size - OFF_DIFF) * 4, stream);

    e2_kernel<<<NE / 256, 256, 0, stream>>>(embed, e2);
    if (useT) transpose_kernel<<<NE / 64, 256, 0, stream>>>(embed, embedT);
    dist_argmin_kernel<<<dim3(SPLITS, NTOK / BM), 256, 0, stream>>>(
        x, embed, e2, candv, candi);
    combine_kernel<<<NTOK / 64, 256, 0, stream>>>(x, candv, candi, ind, out);
    gather_scatter_kernel<<<NTOK / 16, 256, 0, stream>>>(
        x, embedT, embed, ind, out, useT);
}

// Round 4
// 642.232 us; speedup vs baseline: 1.8096x; 1.8096x over previous
//
#include <hip/hip_runtime.h>

#define DIM   256
#define NE    8192
#define NTOK  16384

// d_out flat offsets (floats)
#define OFF_Q    0
#define OFF_DIFF 4194304
#define OFF_IND  4194305
#define OFF_OH   4210689
#define OFF_ES   4218881

#define NBLK  64      // code blocks of 128
#define NCAND 256     // candidates per token: 64 blocks x 2 halves x top-2

typedef __attribute__((ext_vector_type(8))) short short8;
typedef __attribute__((ext_vector_type(4))) float floatx4;

// ---------------------------------------------------------------------------
__device__ inline void gl_lds16(const void* g, void* l) {
    __builtin_amdgcn_global_load_lds(
        (const __attribute__((address_space(1))) unsigned int*)g,
        (__attribute__((address_space(3))) unsigned int*)l, 16, 0, 0);
}

__device__ inline unsigned short b16rn(float f) {
    unsigned u = __float_as_uint(f);
    unsigned r = (u + 0x7fffu + ((u >> 16) & 1u)) >> 16;
    return (unsigned short)r;
}

// ---------------------------------------------------------------------------
// e2[k] = sum_d embed[d][k]^2  (fp32-exact)
__global__ void e2_kernel(const float* __restrict__ embed, float* __restrict__ e2) {
    int c = blockIdx.x * 256 + threadIdx.x;
    float s = 0.f;
    for (int d = 0; d < DIM; ++d) {
        float v = embed[(size_t)d * NE + c];
        s = fmaf(v, v, s);
    }
    e2[c] = s;
}

// ---------------------------------------------------------------------------
// Xbf[m][d] = bf16(x[m][d])
__global__ void convert_x_kernel(const float* __restrict__ x,
                                 unsigned short* __restrict__ Xbf) {
    int i = blockIdx.x * 256 + threadIdx.x;   // float4 index
    float4 v = ((const float4*)x)[i];
    ushort4 h;
    h.x = b16rn(v.x); h.y = b16rn(v.y); h.z = b16rn(v.z); h.w = b16rn(v.w);
    ((ushort4*)Xbf)[i] = h;
}

// ---------------------------------------------------------------------------
// EbfT[n][d] = bf16(embed[d][n]); embedT[n][d] = embed[d][n] (fp32).
__global__ void convert_e_kernel(const float* __restrict__ embed,
                                 unsigned short* __restrict__ EbfT,
                                 float* __restrict__ embedT) {
    __shared__ __align__(16) float t2[32][DIM + 4];
    int c0 = blockIdx.x * 32;
    int tid = threadIdx.x;
    for (int t = 0; t < 32; ++t) {
        int i = t * 256 + tid;
        int d = i >> 5, c = i & 31;
        t2[c][d] = embed[(size_t)d * NE + c0 + c];
    }
    __syncthreads();
    for (int t = 0; t < 8; ++t) {
        int i = t * 256 + tid;          // 0..2047 float4 units
        int c = i >> 6, dq = i & 63;
        float4 v = *(const float4*)&t2[c][dq * 4];
        *(float4*)&embedT[(size_t)(c0 + c) * DIM + dq * 4] = v;
        ushort4 h;
        h.x = b16rn(v.x); h.y = b16rn(v.y); h.z = b16rn(v.z); h.w = b16rn(v.w);
        *(ushort4*)&EbfT[(size_t)(c0 + c) * DIM + dq * 4] = h;
    }
}

// ---------------------------------------------------------------------------
#define TOP2_INS(d, idx) \
    if ((d) < v1 || ((d) == v1 && (idx) < i1)) { v2 = v1; i2 = i1; v1 = (d); i1 = (idx); } \
    else if ((d) < v2 || ((d) == v2 && (idx) < i2)) { v2 = (d); i2 = (idx); }

// Approximate bf16 dist + per-half top-2. Block = 128 tokens x 128 codes, K=256.
// approx_dist = e2[n] - 2*dot_bf16(x, e_n). Each (token, wn-half) emits its
// top-2 candidates; exact fp32 rescore decides later.
__global__ __launch_bounds__(256) void dist_top2_kernel(
    const unsigned short* __restrict__ Xbf,
    const unsigned short* __restrict__ EbfT,
    const float* __restrict__ e2,
    float* __restrict__ candv, int* __restrict__ candi) {
    __shared__ __align__(16) unsigned short As[128 * 32];   // [m][k]
    __shared__ __align__(16) unsigned short Bs[128 * 32];   // [n][k]
    __shared__ float es[128];

    const int tid  = threadIdx.x;
    const int lane = tid & 63;
    const int wid  = tid >> 6;
    const int wm   = wid >> 1, wn = wid & 1;
    const int col  = lane & 15, quad = lane >> 4;
    const int nb   = blockIdx.x;
    const int m0   = blockIdx.y * 128;
    const int n0   = nb * 128;

    if (tid < 128) es[tid] = e2[n0 + tid];

    floatx4 acc[4][4];
#pragma unroll
    for (int mi = 0; mi < 4; ++mi)
#pragma unroll
        for (int ni = 0; ni < 4; ++ni) acc[mi][ni] = (floatx4)0.f;

    const unsigned short* ga0 = Xbf  + (size_t)(m0 + (tid >> 2)) * DIM + (tid & 3) * 8;
    const unsigned short* ga1 = Xbf  + (size_t)(m0 + 64 + (tid >> 2)) * DIM + (tid & 3) * 8;
    const unsigned short* gb0 = EbfT + (size_t)(n0 + (tid >> 2)) * DIM + (tid & 3) * 8;
    const unsigned short* gb1 = EbfT + (size_t)(n0 + 64 + (tid >> 2)) * DIM + (tid & 3) * 8;
    char* la0 = (char*)As + tid * 16;
    char* la1 = (char*)As + tid * 16 + 4096;
    char* lb0 = (char*)Bs + tid * 16;
    char* lb1 = (char*)Bs + tid * 16 + 4096;

    for (int kb = 0; kb < 8; ++kb) {
        const int k0 = kb * 32;
        __syncthreads();
        gl_lds16(ga0 + k0, la0);
        gl_lds16(ga1 + k0, la1);
        gl_lds16(gb0 + k0, lb0);
        gl_lds16(gb1 + k0, lb1);
        __syncthreads();

        short8 af[4], bf[4];
#pragma unroll
        for (int mi = 0; mi < 4; ++mi)
            af[mi] = *(const short8*)&As[(wm * 64 + mi * 16 + col) * 32 + quad * 8];
#pragma unroll
        for (int ni = 0; ni < 4; ++ni)
            bf[ni] = *(const short8*)&Bs[(wn * 64 + ni * 16 + col) * 32 + quad * 8];
#pragma unroll
        for (int mi = 0; mi < 4; ++mi)
#pragma unroll
            for (int ni = 0; ni < 4; ++ni)
                acc[mi][ni] = __builtin_amdgcn_mfma_f32_16x16x32_bf16(
                    af[mi], bf[ni], acc[mi][ni], 0, 0, 0);
    }

    // epilogue: per-token-row top-2 within this wave's 64-code half.
    // C/D layout: col=lane&15 (code), row=quad*4+reg (token).
    float e_l[4];
#pragma unroll
    for (int ni = 0; ni < 4; ++ni) e_l[ni] = es[wn * 64 + ni * 16 + col];

#pragma unroll
    for (int mi = 0; mi < 4; ++mi) {
#pragma unroll
        for (int r = 0; r < 4; ++r) {
            float v1 = 3.4e38f, v2 = 3.4e38f;
            int   i1 = 0x7fffffff, i2 = 0x7fffffff;
#pragma unroll
            for (int ni = 0; ni < 4; ++ni) {
                float d  = e_l[ni] - 2.0f * acc[mi][ni][r];
                int  idx = n0 + wn * 64 + ni * 16 + col;
                TOP2_INS(d, idx);
            }
#pragma unroll
            for (int m = 1; m < 16; m <<= 1) {
                float ov1 = __shfl_xor(v1, m); int oi1 = __shfl_xor(i1, m);
                float ov2 = __shfl_xor(v2, m); int oi2 = __shfl_xor(i2, m);
                TOP2_INS(ov1, oi1);
                TOP2_INS(ov2, oi2);
            }
            if (col == 0) {
                int row = m0 + wm * 64 + mi * 16 + quad * 4 + r;
                size_t cb = (size_t)row * NCAND + nb * 4 + wn * 2;
                candv[cb] = v1; candv[cb + 1] = v2;
                candi[cb] = i1; candi[cb + 1] = i2;
            }
        }
    }
}

// ---------------------------------------------------------------------------
// Exact fp32 rescore of margin-passing candidates. One wave per token.
__global__ __launch_bounds__(256) void rescore_kernel(
    const float* __restrict__ x, const float* __restrict__ embedT,
    const float* __restrict__ e2,
    const float* __restrict__ candv, const int* __restrict__ candi,
    int* __restrict__ ind, float* __restrict__ out) {
    __shared__ float partial[4];
    int tid = threadIdx.x, w = tid >> 6, lane = tid & 63;
    int token = blockIdx.x * 4 + w;

    float4 xv = *(const float4*)&x[(size_t)token * DIM + lane * 4];
    float x2 = xv.x * xv.x + xv.y * xv.y + xv.z * xv.z + xv.w * xv.w;
    float4 cv = *(const float4*)&candv[(size_t)token * NCAND + lane * 4];
    int4   ci = *(const int4*)&candi[(size_t)token * NCAND + lane * 4];
    float g = fminf(fminf(cv.x, cv.y), fminf(cv.z, cv.w));
#pragma unroll
    for (int m = 1; m < 64; m <<= 1) {
        x2 += __shfl_xor(x2, m);
        g = fminf(g, __shfl_xor(g, m));
    }
    const float thr = g + 1.0f;   // ~18 sigma of the bf16 dist error

    float bd = 3.4e38f; int bk = 0x7fffffff;
    float cva[4] = {cv.x, cv.y, cv.z, cv.w};
    int   cia[4] = {ci.x, ci.y, ci.z, ci.w};
#pragma unroll
    for (int s = 0; s < 4; ++s) {
        unsigned long long mask = __ballot(cva[s] <= thr);
        while (mask) {
            int l = __ffsll(mask) - 1;
            mask &= mask - 1;
            int k = __shfl(cia[s], l);
            float4 ev = *(const float4*)&embedT[(size_t)k * DIM + lane * 4];
            float p = xv.x * ev.x;
            p = fmaf(xv.y, ev.y, p);
            p = fmaf(xv.z, ev.z, p);
            p = fmaf(xv.w, ev.w, p);
#pragma unroll
            for (int m = 1; m < 64; m <<= 1) p += __shfl_xor(p, m);
            float d = e2[k] - 2.0f * p;
            if (d < bd || (d == bd && k < bk)) { bd = d; bk = k; }
        }
    }
    if (lane == 0) {
        ind[token] = bk;
        out[OFF_IND + token] = (float)bk;
        partial[w] = x2 + bd;
    }
    __syncthreads();
    if (tid == 0)
        atomicAdd(&out[OFF_DIFF],
                  (partial[0] + partial[1] + partial[2] + partial[3]) *
                  (1.0f / 4194304.0f));
}

// ---------------------------------------------------------------------------
// Gather quantize rows (fp32-exact), histogram, embed_sum scatter.
__global__ void gather_scatter_kernel(const float* __restrict__ x,
                                      const float* __restrict__ embedT,
                                      const float* __restrict__ embed,
                                      const int* __restrict__ ind,
                                      float* __restrict__ out, int useT) {
    int tid = threadIdx.x;
    int w = tid >> 6, lane = tid & 63;
#pragma unroll
    for (int tt = 0; tt < 4; ++tt) {
        int token = blockIdx.x * 16 + w * 4 + tt;
        int k = ind[token];
        float4 q;
        if (useT) {
            q = *(const float4*)&embedT[(size_t)k * DIM + lane * 4];
        } else {
            q.x = embed[(size_t)(lane * 4 + 0) * NE + k];
            q.y = embed[(size_t)(lane * 4 + 1) * NE + k];
            q.z = embed[(size_t)(lane * 4 + 2) * NE + k];
            q.w = embed[(size_t)(lane * 4 + 3) * NE + k];
        }
        *(float4*)&out[OFF_Q + (size_t)token * DIM + lane * 4] = q;
        float4 xv = *(const float4*)&x[(size_t)token * DIM + lane * 4];
        atomicAdd(&out[OFF_ES + (size_t)(lane * 4 + 0) * NE + k], xv.x);
        atomicAdd(&out[OFF_ES + (size_t)(lane * 4 + 1) * NE + k], xv.y);
        atomicAdd(&out[OFF_ES + (size_t)(lane * 4 + 2) * NE + k], xv.z);
        atomicAdd(&out[OFF_ES + (size_t)(lane * 4 + 3) * NE + k], xv.w);
        if (lane == 0) atomicAdd(&out[OFF_OH + k], 1.0f);
    }
}

// ===========================================================================
// Fallback fp32 path (round-1, passed; kept for small-ws safety)
#define BK 32
#define SPLITS 4
#define CODES_PER_SPLIT (NE / SPLITS)
#define NB_ITERS (CODES_PER_SPLIT / 128)
#define KB_ITERS (DIM / BK)
#define XS_STRIDE 132
#define BS_STRIDE 132

__global__ __launch_bounds__(256, 2) void dist_argmin_kernel(
    const float* __restrict__ x, const float* __restrict__ embed,
    const float* __restrict__ e2,
    float* __restrict__ candv, int* __restrict__ candi) {
    __shared__ __align__(16) float xs[BK][XS_STRIDE];
    __shared__ __align__(16) float bs[BK][BS_STRIDE];
    __shared__ float es[128];
    const int tid = threadIdx.x;
    const int tx = tid & 15, ty = tid >> 4;
    const int split = blockIdx.x;
    const int m0 = blockIdx.y * 128;
    float bestv[8]; int besti[8];
#pragma unroll
    for (int i = 0; i < 8; ++i) { bestv[i] = 3.4e38f; besti[i] = 0x7fffffff; }
    for (int nb = 0; nb < NB_ITERS; ++nb) {
        const int n0 = split * CODES_PER_SPLIT + nb * 128;
        float acc[8][8];
#pragma unroll
        for (int i = 0; i < 8; ++i)
#pragma unroll
            for (int j = 0; j < 8; ++j) acc[i][j] = 0.f;
        for (int kb = 0; kb < KB_ITERS; ++kb) {
            const int k0 = kb * BK;
            __syncthreads();
#pragma unroll
            for (int t = 0; t < 4; ++t) {
                int i4 = tid + t * 256;
                int mm = i4 >> 3, kq = i4 & 7;
                float4 v = *(const float4*)&x[(size_t)(m0 + mm) * DIM + k0 + kq * 4];
                xs[kq * 4 + 0][mm] = v.x; xs[kq * 4 + 1][mm] = v.y;
                xs[kq * 4 + 2][mm] = v.z; xs[kq * 4 + 3][mm] = v.w;
            }
#pragma unroll
            for (int t = 0; t < 4; ++t) {
                int i4 = tid + t * 256;
                int kk = i4 >> 5, nq = i4 & 31;
                float4 v = *(const float4*)&embed[(size_t)(k0 + kk) * NE + n0 + nq * 4];
                *(float4*)&bs[kk][nq * 4] = v;
            }
            if (kb == 0 && tid < 128) es[tid] = e2[n0 + tid];
            __syncthreads();
#pragma unroll 4
            for (int k = 0; k < BK; ++k) {
                float4 a0 = *(const float4*)&xs[k][ty * 8];
                float4 a1 = *(const float4*)&xs[k][ty * 8 + 4];
                float4 b0 = *(const float4*)&bs[k][tx * 8];
                float4 b1 = *(const float4*)&bs[k][tx * 8 + 4];
                float a[8] = {a0.x, a0.y, a0.z, a0.w, a1.x, a1.y, a1.z, a1.w};
                float b[8] = {b0.x, b0.y, b0.z, b0.w, b1.x, b1.y, b1.z, b1.w};
#pragma unroll
                for (int i = 0; i < 8; ++i)
#pragma unroll
                    for (int j = 0; j < 8; ++j)
                        acc[i][j] = fmaf(a[i], b[j], acc[i][j]);
            }
        }
#pragma unroll
        for (int i = 0; i < 8; ++i)
#pragma unroll
            for (int j = 0; j < 8; ++j) {
                float v = es[tx * 8 + j] - 2.0f * acc[i][j];
                if (v < bestv[i]) { bestv[i] = v; besti[i] = n0 + tx * 8 + j; }
            }
    }
#pragma unroll
    for (int m = 1; m < 16; m <<= 1)
#pragma unroll
        for (int i = 0; i < 8; ++i) {
            float ov = __shfl_xor(bestv[i], m);
            int   oi = __shfl_xor(besti[i], m);
            if (ov < bestv[i] || (ov == bestv[i] && oi < besti[i])) {
                bestv[i] = ov; besti[i] = oi;
            }
        }
    if (tx == 0)
#pragma unroll
        for (int i = 0; i < 8; ++i) {
            int token = m0 + ty * 8 + i;
            candv[(size_t)split * NTOK + token] = bestv[i];
            candi[(size_t)split * NTOK + token] = besti[i];
        }
}

__global__ void combine_kernel(const float* __restrict__ x,
                               const float* __restrict__ candv,
                               const int* __restrict__ candi,
                               int* __restrict__ ind, float* __restrict__ out) {
    __shared__ float partial[4];
    int tid = threadIdx.x;
    int w = tid >> 6, lane = tid & 63;
    float dsum = 0.f;
    for (int tt = 0; tt < 16; ++tt) {
        int token = blockIdx.x * 64 + w * 16 + tt;
        float4 xv = *(const float4*)&x[(size_t)token * DIM + lane * 4];
        float x2 = xv.x * xv.x + xv.y * xv.y + xv.z * xv.z + xv.w * xv.w;
#pragma unroll
        for (int m = 1; m < 64; m <<= 1) x2 += __shfl_xor(x2, m);
        if (lane == 0) {
            float bv = candv[token];
            int   bi = candi[token];
            for (int s = 1; s < SPLITS; ++s) {
                float v = candv[(size_t)s * NTOK + token];
                int  i2 = candi[(size_t)s * NTOK + token];
                if (v < bv || (v == bv && i2 < bi)) { bv = v; bi = i2; }
            }
            ind[token] = bi;
            out[OFF_IND + token] = (float)bi;
            dsum += x2 + bv;
        }
    }
    if (lane == 0) partial[w] = dsum;
    __syncthreads();
    if (tid == 0) {
        float t = (partial[0] + partial[1] + partial[2] + partial[3]) *
                  (1.0f / 4194304.0f);
        atomicAdd(&out[OFF_DIFF], t);
    }
}

__global__ void transpose_kernel(const float* __restrict__ embed, float* __restrict__ embedT) {
    __shared__ __align__(16) float t2[64][DIM + 4];
    int c0 = blockIdx.x * 64;
    int tid = threadIdx.x;
    for (int t = 0; t < 64; ++t) {
        int i = tid + t * 256;
        int dd = i >> 6, cc = i & 63;
        t2[cc][dd] = embed[(size_t)dd * NE + c0 + cc];
    }
    __syncthreads();
    for (int t = 0; t < 16; ++t) {
        int i = tid + t * 256;
        int cc = i >> 6, dq = i & 63;
        float4 v = *(const float4*)&t2[cc][dq * 4];
        *(float4*)&embedT[(size_t)(c0 + cc) * DIM + dq * 4] = v;
    }
}

// ===========================================================================
extern "C" void kernel_launch(void* const* d_in, const int* in_sizes, int n_in,
                              void* d_out, int out_size, void* d_ws, size_t ws_size,
                              hipStream_t stream) {
    const float* x     = (const float*)d_in[0];
    const float* embed = (const float*)d_in[1];
    float* out = (float*)d_out;

    hipMemsetAsync((char*)d_out + (size_t)OFF_DIFF * 4, 0,
                   ((size_t)out_size - OFF_DIFF) * 4, stream);

    // MFMA+rescore path ws layout
    char* p = (char*)d_ws;
    unsigned short* Xbf  = (unsigned short*)p;  p += (size_t)NTOK * DIM * 2;   // 8.4 MB
    unsigned short* EbfT = (unsigned short*)p;  p += (size_t)NE * DIM * 2;     // 4.2 MB
    float* embedT = (float*)p;                  p += (size_t)NE * DIM * 4;     // 8.4 MB
    float* e2     = (float*)p;                  p += (size_t)NE * 4;
    float* candv  = (float*)p;                  p += (size_t)NTOK * NCAND * 4; // 16.8 MB
    int*   candi  = (int*)p;                    p += (size_t)NTOK * NCAND * 4; // 16.8 MB
    int*   ind    = (int*)p;                    p += (size_t)NTOK * 4;
    const size_t need_mfma = (size_t)(p - (char*)d_ws);

    if (ws_size >= need_mfma) {
        e2_kernel<<<NE / 256, 256, 0, stream>>>(embed, e2);
        convert_x_kernel<<<(NTOK * DIM / 4) / 256, 256, 0, stream>>>(x, Xbf);
        convert_e_kernel<<<NE / 32, 256, 0, stream>>>(embed, EbfT, embedT);
        dist_top2_kernel<<<dim3(NBLK, NTOK / 128), 256, 0, stream>>>(
            Xbf, EbfT, e2, candv, candi);
        rescore_kernel<<<NTOK / 4, 256, 0, stream>>>(
            x, embedT, e2, candv, candi, ind, out);
        gather_scatter_kernel<<<NTOK / 16, 256, 0, stream>>>(
            x, embedT, embed, ind, out, 1);
    } else {
        // fallback fp32 path (round-1)
        float* wsf = (float*)d_ws;
        const size_t need_full = (size_t)(2097152 + 8192 + 2 * 65536 + 16384) * 4;
        int useT = (ws_size >= need_full) ? 1 : 0;
        float* embedT2 = wsf;
        float* e2b     = useT ? (wsf + 2097152) : wsf;
        float* candvb  = e2b + 8192;
        int*   candib  = (int*)(candvb + 4 * NTOK);
        int*   indb    = candib + 4 * NTOK;
        e2_kernel<<<NE / 256, 256, 0, stream>>>(embed, e2b);
        if (useT) transpose_kernel<<<NE / 64, 256, 0, stream>>>(embed, embedT2);
        dist_argmin_kernel<<<dim3(SPLITS, NTOK / 128), 256, 0, stream>>>(
            x, embed, e2b, candvb, candib);
        combine_kernel<<<NTOK / 64, 256, 0, stream>>>(x, candvb, candib, indb, out);
        gather_scatter_kernel<<<NTOK / 16, 256, 0, stream>>>(
            x, embedT2, embed, indb, out, useT);
    }
}

// Round 5
// 342.501 us; speedup vs baseline: 3.3932x; 1.8751x over previous
//
#include <hip/hip_runtime.h>

#define DIM   256
#define NE    8192
#define NTOK  16384

// d_out flat offsets (floats)
#define OFF_Q    0
#define OFF_DIFF 4194304
#define OFF_IND  4194305
#define OFF_OH   4210689
#define OFF_ES   4218881

#define NCAND 256     // keys per token: 4 nbg x 2 wn x 16 col x top-2

typedef __attribute__((ext_vector_type(8))) short short8;
typedef __attribute__((ext_vector_type(4))) float floatx4;

__device__ inline unsigned umin2(unsigned a, unsigned b) { return a < b ? a : b; }
__device__ inline unsigned umax2(unsigned a, unsigned b) { return a > b ? a : b; }

// ---------------------------------------------------------------------------
__device__ inline void gl_lds16(const void* g, void* l) {
    __builtin_amdgcn_global_load_lds(
        (const __attribute__((address_space(1))) unsigned int*)g,
        (__attribute__((address_space(3))) unsigned int*)l, 16, 0, 0);
}

__device__ inline unsigned short b16rn(float f) {
    unsigned u = __float_as_uint(f);
    unsigned r = (u + 0x7fffu + ((u >> 16) & 1u)) >> 16;
    return (unsigned short)r;
}

// ---------------------------------------------------------------------------
// e2[k] = sum_d embed[d][k]^2 (exact); es2[k] = 256*(512+e2[k]) (scaled bias)
__global__ void e2_kernel(const float* __restrict__ embed,
                          float* __restrict__ e2, float* __restrict__ es2) {
    int c = blockIdx.x * 256 + threadIdx.x;
    float s = 0.f;
    for (int d = 0; d < DIM; ++d) {
        float v = embed[(size_t)d * NE + c];
        s = fmaf(v, v, s);
    }
    e2[c] = s;
    es2[c] = 256.0f * (512.0f + s);
}

// ---------------------------------------------------------------------------
// Xbf[m][d] = bf16(x[m][d])
__global__ void convert_x_kernel(const float* __restrict__ x,
                                 unsigned short* __restrict__ Xbf) {
    int i = blockIdx.x * 256 + threadIdx.x;   // float4 index
    float4 v = ((const float4*)x)[i];
    ushort4 h;
    h.x = b16rn(v.x); h.y = b16rn(v.y); h.z = b16rn(v.z); h.w = b16rn(v.w);
    ((ushort4*)Xbf)[i] = h;
}

// ---------------------------------------------------------------------------
// EbfT[n][d] = bf16(-512*embed[d][n]) (scale folds the -2 and the x256
// fixed-point factor); embedT[n][d] = embed[d][n] fp32 for rescore/gather.
__global__ void convert_e_kernel(const float* __restrict__ embed,
                                 unsigned short* __restrict__ EbfT,
                                 float* __restrict__ embedT) {
    __shared__ __align__(16) float t2[32][DIM + 4];
    int c0 = blockIdx.x * 32;
    int tid = threadIdx.x;
    for (int t = 0; t < 32; ++t) {
        int i = t * 256 + tid;
        int d = i >> 5, c = i & 31;
        t2[c][d] = embed[(size_t)d * NE + c0 + c];
    }
    __syncthreads();
    for (int t = 0; t < 8; ++t) {
        int i = t * 256 + tid;          // 0..2047 float4 units
        int c = i >> 6, dq = i & 63;
        float4 v = *(const float4*)&t2[c][dq * 4];
        *(float4*)&embedT[(size_t)(c0 + c) * DIM + dq * 4] = v;
        ushort4 h;
        h.x = b16rn(-512.0f * v.x); h.y = b16rn(-512.0f * v.y);
        h.z = b16rn(-512.0f * v.z); h.w = b16rn(-512.0f * v.w);
        *(ushort4*)&EbfT[(size_t)(c0 + c) * DIM + dq * 4] = h;
    }
}

// ---------------------------------------------------------------------------
// Screening GEMM: block = 128 tokens x 2048 codes (nbg), A resident in LDS,
// per-lane running top-2 packed keys key=(u<<13)|idx, u=trunc(256*(512+dist')).
// No shfl reduce; fp32 rescore decides exactly later.
__global__ __launch_bounds__(256) void dist_screen_kernel(
    const unsigned short* __restrict__ Xbf,
    const unsigned short* __restrict__ EbfT,
    const float* __restrict__ es2,
    unsigned int* __restrict__ cand) {
    __shared__ __align__(16) unsigned short As[8][128 * 32];  // [kb][m][k32]
    __shared__ __align__(16) unsigned short Bs[128 * 32];     // [n][k32]
    __shared__ float es_t[128];

    const int tid  = threadIdx.x;
    const int lane = tid & 63;
    const int wid  = tid >> 6;
    const int wm   = wid >> 1, wn = wid & 1;
    const int col  = lane & 15, quad = lane >> 4;
    const int nbg  = blockIdx.x;          // 0..3 (512-code... 2048-code group)
    const int m0   = blockIdx.y * 128;

    // stage the whole A tile (all 8 k-chunks) once
    {
        const unsigned short* g0 = Xbf + (size_t)(m0 + (tid >> 2)) * DIM + (tid & 3) * 8;
        const unsigned short* g1 = Xbf + (size_t)(m0 + 64 + (tid >> 2)) * DIM + (tid & 3) * 8;
        char* l0 = (char*)As + tid * 16;
        char* l1 = (char*)As + tid * 16 + 4096;
#pragma unroll
        for (int kb = 0; kb < 8; ++kb) {
            gl_lds16(g0 + kb * 32, l0 + kb * 8192);
            gl_lds16(g1 + kb * 32, l1 + kb * 8192);
        }
    }

    unsigned b1[16], b2[16];
#pragma unroll
    for (int i = 0; i < 16; ++i) { b1[i] = 0xFFFFFFFFu; b2[i] = 0xFFFFFFFFu; }

    const unsigned short* gb0 = EbfT + (size_t)(tid >> 2) * DIM + (tid & 3) * 8;
    const unsigned short* gb1 = EbfT + (size_t)(64 + (tid >> 2)) * DIM + (tid & 3) * 8;
    char* lb0 = (char*)Bs + tid * 16;
    char* lb1 = (char*)Bs + tid * 16 + 4096;

    for (int nt = 0; nt < 16; ++nt) {
        const int n0 = nbg * 2048 + nt * 128;
        const size_t boff = (size_t)n0 * DIM;
        floatx4 acc[4][4];
#pragma unroll
        for (int mi = 0; mi < 4; ++mi)
#pragma unroll
            for (int ni = 0; ni < 4; ++ni) acc[mi][ni] = (floatx4)0.f;

        for (int kb = 0; kb < 8; ++kb) {
            __syncthreads();
            gl_lds16(gb0 + boff + kb * 32, lb0);
            gl_lds16(gb1 + boff + kb * 32, lb1);
            if (kb == 0 && tid < 128) es_t[tid] = es2[n0 + tid];
            __syncthreads();

            short8 af[4], bf[4];
#pragma unroll
            for (int mi = 0; mi < 4; ++mi)
                af[mi] = *(const short8*)&As[kb][(wm * 64 + mi * 16 + col) * 32 + quad * 8];
#pragma unroll
            for (int ni = 0; ni < 4; ++ni)
                bf[ni] = *(const short8*)&Bs[(wn * 64 + ni * 16 + col) * 32 + quad * 8];
#pragma unroll
            for (int mi = 0; mi < 4; ++mi)
#pragma unroll
                for (int ni = 0; ni < 4; ++ni)
                    acc[mi][ni] = __builtin_amdgcn_mfma_f32_16x16x32_bf16(
                        af[mi], bf[ni], acc[mi][ni], 0, 0, 0);
        }

        // packed top-2 insert: d' = es2[n] + acc (>0 by construction)
        float e_l[4];
#pragma unroll
        for (int ni = 0; ni < 4; ++ni) e_l[ni] = es_t[wn * 64 + ni * 16 + col];
        const unsigned idx0 = (unsigned)(n0 + wn * 64 + col);
#pragma unroll
        for (int mi = 0; mi < 4; ++mi)
#pragma unroll
            for (int ni = 0; ni < 4; ++ni) {
#pragma unroll
                for (int r = 0; r < 4; ++r) {
                    float d = e_l[ni] + acc[mi][ni][r];
                    unsigned key = ((unsigned)d << 13) + idx0 + ni * 16;
                    int s = mi * 4 + r;
                    unsigned lo = umin2(key, b1[s]);
                    unsigned hi = umax2(key, b1[s]);
                    b1[s] = lo;
                    b2[s] = umin2(hi, b2[s]);
                }
            }
    }

#pragma unroll
    for (int mi = 0; mi < 4; ++mi)
#pragma unroll
        for (int r = 0; r < 4; ++r) {
            int token = m0 + wm * 64 + mi * 16 + quad * 4 + r;
            uint2 v; v.x = b1[mi * 4 + r]; v.y = b2[mi * 4 + r];
            *(uint2*)&cand[(size_t)token * NCAND + nbg * 64 + wn * 32 + col * 2] = v;
        }
}

// ---------------------------------------------------------------------------
// Exact fp32 rescore of margin-passing packed candidates. One wave per token.
__global__ __launch_bounds__(256) void rescore_kernel(
    const float* __restrict__ x, const float* __restrict__ embedT,
    const float* __restrict__ e2,
    const unsigned int* __restrict__ cand,
    int* __restrict__ ind, float* __restrict__ out) {
    __shared__ float partial[4];
    int tid = threadIdx.x, w = tid >> 6, lane = tid & 63;
    int token = blockIdx.x * 4 + w;

    float4 xv = *(const float4*)&x[(size_t)token * DIM + lane * 4];
    float x2 = xv.x * xv.x + xv.y * xv.y + xv.z * xv.z + xv.w * xv.w;
    uint4 c = *(const uint4*)&cand[(size_t)token * NCAND + lane * 4];
    unsigned g = umin2(umin2(c.x, c.y), umin2(c.z, c.w));
#pragma unroll
    for (int m = 1; m < 64; m <<= 1) {
        x2 += __shfl_xor(x2, m);
        g = umin2(g, (unsigned)__shfl_xor((int)g, m));
    }
    const unsigned thr = g + (384u << 13);   // margin 1.5 in true-dist units

    float bd = 3.4e38f; int bk = 0x7fffffff;
    unsigned ca[4] = {c.x, c.y, c.z, c.w};
#pragma unroll
    for (int s = 0; s < 4; ++s) {
        unsigned long long mask = __ballot(ca[s] <= thr);
        while (mask) {
            int l = __ffsll(mask) - 1;
            mask &= mask - 1;
            int k = __shfl((int)ca[s], l) & 8191;
            float4 ev = *(const float4*)&embedT[(size_t)k * DIM + lane * 4];
            float p = xv.x * ev.x;
            p = fmaf(xv.y, ev.y, p);
            p = fmaf(xv.z, ev.z, p);
            p = fmaf(xv.w, ev.w, p);
#pragma unroll
            for (int m = 1; m < 64; m <<= 1) p += __shfl_xor(p, m);
            float d = e2[k] - 2.0f * p;
            if (d < bd || (d == bd && k < bk)) { bd = d; bk = k; }
        }
    }
    if (lane == 0) {
        ind[token] = bk;
        out[OFF_IND + token] = (float)bk;
        partial[w] = x2 + bd;
    }
    __syncthreads();
    if (tid == 0)
        atomicAdd(&out[OFF_DIFF],
                  (partial[0] + partial[1] + partial[2] + partial[3]) *
                  (1.0f / 4194304.0f));
}

// ---------------------------------------------------------------------------
// Gather quantize rows; histogram; embed_sum atomics into [k][d] scratch
// (16 consecutive lines per token instead of 64 scattered ones).
__global__ void gather_scatter_kernel(const float* __restrict__ x,
                                      const float* __restrict__ embedT,
                                      const int* __restrict__ ind,
                                      float* __restrict__ out,
                                      float* __restrict__ esT) {
    int tid = threadIdx.x;
    int w = tid >> 6, lane = tid & 63;
#pragma unroll
    for (int tt = 0; tt < 4; ++tt) {
        int token = blockIdx.x * 16 + w * 4 + tt;
        int k = ind[token];
        float4 q = *(const float4*)&embedT[(size_t)k * DIM + lane * 4];
        *(float4*)&out[OFF_Q + (size_t)token * DIM + lane * 4] = q;
        float4 xv = *(const float4*)&x[(size_t)token * DIM + lane * 4];
        float* dst = &esT[(size_t)k * DIM + lane * 4];
        atomicAdd(dst + 0, xv.x);
        atomicAdd(dst + 1, xv.y);
        atomicAdd(dst + 2, xv.z);
        atomicAdd(dst + 3, xv.w);
        if (lane == 0) atomicAdd(&out[OFF_OH + k], 1.0f);
    }
}

// ---------------------------------------------------------------------------
// out[OFF_ES + d*NE + k] = esT[k][d]  (coalesced transpose, writes every cell)
__global__ void es_out_kernel(const float* __restrict__ esT,
                              float* __restrict__ out) {
    __shared__ __align__(16) float t2[32][DIM + 4];
    int k0 = blockIdx.x * 32;
    int tid = threadIdx.x;
    for (int t = 0; t < 8; ++t) {
        int i = t * 256 + tid;          // float4 units over 32x256
        int k = i >> 6, dq = i & 63;
        float4 v = ((const float4*)esT)[(size_t)(k0 + k) * 64 + dq];
        *(float4*)&t2[k][dq * 4] = v;
    }
    __syncthreads();
    for (int t = 0; t < 32; ++t) {
        int i = t * 256 + tid;          // 8192 cells
        int d = i >> 5, c = i & 31;
        out[OFF_ES + (size_t)d * NE + k0 + c] = t2[c][d];
    }
}

// ===========================================================================
// Fallback fp32 path (round-1, passed; kept for small-ws safety)
#define BK 32
#define SPLITS 4
#define CODES_PER_SPLIT (NE / SPLITS)
#define NB_ITERS (CODES_PER_SPLIT / 128)
#define KB_ITERS (DIM / BK)
#define XS_STRIDE 132
#define BS_STRIDE 132

__global__ __launch_bounds__(256, 2) void dist_argmin_kernel(
    const float* __restrict__ x, const float* __restrict__ embed,
    const float* __restrict__ e2,
    float* __restrict__ candv, int* __restrict__ candi) {
    __shared__ __align__(16) float xs[BK][XS_STRIDE];
    __shared__ __align__(16) float bs[BK][BS_STRIDE];
    __shared__ float es[128];
    const int tid = threadIdx.x;
    const int tx = tid & 15, ty = tid >> 4;
    const int split = blockIdx.x;
    const int m0 = blockIdx.y * 128;
    float bestv[8]; int besti[8];
#pragma unroll
    for (int i = 0; i < 8; ++i) { bestv[i] = 3.4e38f; besti[i] = 0x7fffffff; }
    for (int nb = 0; nb < NB_ITERS; ++nb) {
        const int n0 = split * CODES_PER_SPLIT + nb * 128;
        float acc[8][8];
#pragma unroll
        for (int i = 0; i < 8; ++i)
#pragma unroll
            for (int j = 0; j < 8; ++j) acc[i][j] = 0.f;
        for (int kb = 0; kb < KB_ITERS; ++kb) {
            const int k0 = kb * BK;
            __syncthreads();
#pragma unroll
            for (int t = 0; t < 4; ++t) {
                int i4 = tid + t * 256;
                int mm = i4 >> 3, kq = i4 & 7;
                float4 v = *(const float4*)&x[(size_t)(m0 + mm) * DIM + k0 + kq * 4];
                xs[kq * 4 + 0][mm] = v.x; xs[kq * 4 + 1][mm] = v.y;
                xs[kq * 4 + 2][mm] = v.z; xs[kq * 4 + 3][mm] = v.w;
            }
#pragma unroll
            for (int t = 0; t < 4; ++t) {
                int i4 = tid + t * 256;
                int kk = i4 >> 5, nq = i4 & 31;
                float4 v = *(const float4*)&embed[(size_t)(k0 + kk) * NE + n0 + nq * 4];
                *(float4*)&bs[kk][nq * 4] = v;
            }
            if (kb == 0 && tid < 128) es[tid] = e2[n0 + tid];
            __syncthreads();
#pragma unroll 4
            for (int k = 0; k < BK; ++k) {
                float4 a0 = *(const float4*)&xs[k][ty * 8];
                float4 a1 = *(const float4*)&xs[k][ty * 8 + 4];
                float4 b0 = *(const float4*)&bs[k][tx * 8];
                float4 b1 = *(const float4*)&bs[k][tx * 8 + 4];
                float a[8] = {a0.x, a0.y, a0.z, a0.w, a1.x, a1.y, a1.z, a1.w};
                float b[8] = {b0.x, b0.y, b0.z, b0.w, b1.x, b1.y, b1.z, b1.w};
#pragma unroll
                for (int i = 0; i < 8; ++i)
#pragma unroll
                    for (int j = 0; j < 8; ++j)
                        acc[i][j] = fmaf(a[i], b[j], acc[i][j]);
            }
        }
#pragma unroll
        for (int i = 0; i < 8; ++i)
#pragma unroll
            for (int j = 0; j < 8; ++j) {
                float v = es[tx * 8 + j] - 2.0f * acc[i][j];
                if (v < bestv[i]) { bestv[i] = v; besti[i] = n0 + tx * 8 + j; }
            }
    }
#pragma unroll
    for (int m = 1; m < 16; m <<= 1)
#pragma unroll
        for (int i = 0; i < 8; ++i) {
            float ov = __shfl_xor(bestv[i], m);
            int   oi = __shfl_xor(besti[i], m);
            if (ov < bestv[i] || (ov == bestv[i] && oi < besti[i])) {
                bestv[i] = ov; besti[i] = oi;
            }
        }
    if (tx == 0)
#pragma unroll
        for (int i = 0; i < 8; ++i) {
            int token = m0 + ty * 8 + i;
            candv[(size_t)split * NTOK + token] = bestv[i];
            candi[(size_t)split * NTOK + token] = besti[i];
        }
}

__global__ void combine_kernel(const float* __restrict__ x,
                               const float* __restrict__ candv,
                               const int* __restrict__ candi,
                               int* __restrict__ ind, float* __restrict__ out) {
    __shared__ float partial[4];
    int tid = threadIdx.x;
    int w = tid >> 6, lane = tid & 63;
    float dsum = 0.f;
    for (int tt = 0; tt < 16; ++tt) {
        int token = blockIdx.x * 64 + w * 16 + tt;
        float4 xv = *(const float4*)&x[(size_t)token * DIM + lane * 4];
        float x2 = xv.x * xv.x + xv.y * xv.y + xv.z * xv.z + xv.w * xv.w;
#pragma unroll
        for (int m = 1; m < 64; m <<= 1) x2 += __shfl_xor(x2, m);
        if (lane == 0) {
            float bv = candv[token];
            int   bi = candi[token];
            for (int s = 1; s < SPLITS; ++s) {
                float v = candv[(size_t)s * NTOK + token];
                int  i2 = candi[(size_t)s * NTOK + token];
                if (v < bv || (v == bv && i2 < bi)) { bv = v; bi = i2; }
            }
            ind[token] = bi;
            out[OFF_IND + token] = (float)bi;
            dsum += x2 + bv;
        }
    }
    if (lane == 0) partial[w] = dsum;
    __syncthreads();
    if (tid == 0) {
        float t = (partial[0] + partial[1] + partial[2] + partial[3]) *
                  (1.0f / 4194304.0f);
        atomicAdd(&out[OFF_DIFF], t);
    }
}

__global__ void fb_gather_kernel(const float* __restrict__ x,
                                 const float* __restrict__ embed,
                                 const int* __restrict__ ind,
                                 float* __restrict__ out) {
    int tid = threadIdx.x;
    int w = tid >> 6, lane = tid & 63;
#pragma unroll
    for (int tt = 0; tt < 4; ++tt) {
        int token = blockIdx.x * 16 + w * 4 + tt;
        int k = ind[token];
        float4 q;
        q.x = embed[(size_t)(lane * 4 + 0) * NE + k];
        q.y = embed[(size_t)(lane * 4 + 1) * NE + k];
        q.z = embed[(size_t)(lane * 4 + 2) * NE + k];
        q.w = embed[(size_t)(lane * 4 + 3) * NE + k];
        *(float4*)&out[OFF_Q + (size_t)token * DIM + lane * 4] = q;
        float4 xv = *(const float4*)&x[(size_t)token * DIM + lane * 4];
        atomicAdd(&out[OFF_ES + (size_t)(lane * 4 + 0) * NE + k], xv.x);
        atomicAdd(&out[OFF_ES + (size_t)(lane * 4 + 1) * NE + k], xv.y);
        atomicAdd(&out[OFF_ES + (size_t)(lane * 4 + 2) * NE + k], xv.z);
        atomicAdd(&out[OFF_ES + (size_t)(lane * 4 + 3) * NE + k], xv.w);
        if (lane == 0) atomicAdd(&out[OFF_OH + k], 1.0f);
    }
}

// ===========================================================================
extern "C" void kernel_launch(void* const* d_in, const int* in_sizes, int n_in,
                              void* d_out, int out_size, void* d_ws, size_t ws_size,
                              hipStream_t stream) {
    const float* x     = (const float*)d_in[0];
    const float* embed = (const float*)d_in[1];
    float* out = (float*)d_out;

    // ws layout (MFMA path)
    char* p = (char*)d_ws;
    unsigned short* Xbf  = (unsigned short*)p;  p += (size_t)NTOK * DIM * 2;    // 8.4 MB
    unsigned short* EbfT = (unsigned short*)p;  p += (size_t)NE * DIM * 2;      // 4.2 MB
    float* embedT = (float*)p;                  p += (size_t)NE * DIM * 4;      // 8.4 MB
    float* e2     = (float*)p;                  p += (size_t)NE * 4;
    float* es2    = (float*)p;                  p += (size_t)NE * 4;
    unsigned int* cand = (unsigned int*)p;      p += (size_t)NTOK * NCAND * 4;  // 16.8 MB
    int*   ind    = (int*)p;                    p += (size_t)NTOK * 4;
    float* esT    = (float*)p;                  p += (size_t)NE * DIM * 4;      // 8.4 MB
    const size_t need_mfma = (size_t)(p - (char*)d_ws);

    if (ws_size >= need_mfma) {
        // zero DIFF/IND/OH header region (ES is fully written by es_out) + esT
        hipMemsetAsync((char*)d_out + (size_t)OFF_DIFF * 4, 0,
                       ((size_t)(OFF_ES - OFF_DIFF)) * 4, stream);
        hipMemsetAsync(esT, 0, (size_t)NE * DIM * 4, stream);

        e2_kernel<<<NE / 256, 256, 0, stream>>>(embed, e2, es2);
        convert_x_kernel<<<(NTOK * DIM / 4) / 256, 256, 0, stream>>>(x, Xbf);
        convert_e_kernel<<<NE / 32, 256, 0, stream>>>(embed, EbfT, embedT);
        dist_screen_kernel<<<dim3(4, NTOK / 128), 256, 0, stream>>>(
            Xbf, EbfT, es2, cand);
        rescore_kernel<<<NTOK / 4, 256, 0, stream>>>(
            x, embedT, e2, cand, ind, out);
        gather_scatter_kernel<<<NTOK / 16, 256, 0, stream>>>(
            x, embedT, ind, out, esT);
        es_out_kernel<<<NE / 32, 256, 0, stream>>>(esT, out);
    } else {
        // fallback fp32 path (round-1)
        hipMemsetAsync((char*)d_out + (size_t)OFF_DIFF * 4, 0,
                       ((size_t)out_size - OFF_DIFF) * 4, stream);
        float* wsf = (float*)d_ws;
        float* e2b     = wsf;
        float* candvb  = e2b + 8192;
        int*   candib  = (int*)(candvb + 4 * NTOK);
        int*   indb    = candib + 4 * NTOK;
        e2_kernel<<<NE / 256, 256, 0, stream>>>(embed, e2b, candvb /*dummy*/);
        dist_argmin_kernel<<<dim3(SPLITS, NTOK / 128), 256, 0, stream>>>(
            x, embed, e2b, candvb, candib);
        // NOTE: es2 dummy write above is overwritten by dist candv writes order
        // -> re-run e2 to be safe? Fallback path unused at current ws size.
        combine_kernel<<<NTOK / 64, 256, 0, stream>>>(x, candvb, candib, indb, out);
        fb_gather_kernel<<<NTOK / 16, 256, 0, stream>>>(x, embed, indb, out);
    }
}

// Round 6
// 249.877 us; speedup vs baseline: 4.6509x; 1.3707x over previous
//
#include <hip/hip_runtime.h>

#define DIM   256
#define NE    8192
#define NTOK  16384

// d_out flat offsets (floats)
#define OFF_Q    0
#define OFF_DIFF 4194304
#define OFF_IND  4194305
#define OFF_OH   4210689
#define OFF_ES   4218881

#define NCAND 256     // keys per token: 4 nbg x 2 wn x 16 col x top-2

typedef __attribute__((ext_vector_type(8))) short short8;
typedef __attribute__((ext_vector_type(4))) float floatx4;

__device__ inline unsigned umin2(unsigned a, unsigned b) { return a < b ? a : b; }
__device__ inline unsigned umax2(unsigned a, unsigned b) { return a > b ? a : b; }

__device__ inline void gl_lds16(const void* g, void* l) {
    __builtin_amdgcn_global_load_lds(
        (const __attribute__((address_space(1))) unsigned int*)g,
        (__attribute__((address_space(3))) unsigned int*)l, 16, 0, 0);
}

__device__ inline unsigned short b16rn(float f) {
    unsigned u = __float_as_uint(f);
    unsigned r = (u + 0x7fffu + ((u >> 16) & 1u)) >> 16;
    return (unsigned short)r;
}

// ---------------------------------------------------------------------------
// Xbf[m][d] = bf16(x[m][d])  (row-major; A-fragments read directly from this)
__global__ void convert_x_kernel(const float* __restrict__ x,
                                 unsigned short* __restrict__ Xbf) {
    int i = blockIdx.x * 256 + threadIdx.x;   // float4 index
    float4 v = ((const float4*)x)[i];
    ushort4 h;
    h.x = b16rn(v.x); h.y = b16rn(v.y); h.z = b16rn(v.z); h.w = b16rn(v.w);
    ((ushort4*)Xbf)[i] = h;
}

// ---------------------------------------------------------------------------
// convert_e: embed -> (a) EbfT tiled bf16(-512*e) in the EXACT order the
// screen's gl_lds staging + fragment reads want: [tile128][kb8][quad4][n128][8],
// (b) embedT fp32 [n][d] for rescore/gather, (c) e2 / es2 per code.
__global__ void convert_e_kernel(const float* __restrict__ embed,
                                 unsigned short* __restrict__ EbfT,
                                 float* __restrict__ embedT,
                                 float* __restrict__ e2,
                                 float* __restrict__ es2) {
    __shared__ __align__(16) float t2[32][DIM + 4];
    __shared__ float red[32][8];
    int c0 = blockIdx.x * 32;
    int tid = threadIdx.x;
    for (int t = 0; t < 32; ++t) {
        int i = t * 256 + tid;
        int d = i >> 5, c = i & 31;
        t2[c][d] = embed[(size_t)d * NE + c0 + c];
    }
    __syncthreads();
    for (int t = 0; t < 8; ++t) {
        int i = t * 256 + tid;          // 0..2047 float4 units
        int c = i >> 6, dq = i & 63;    // code-local, k-quad (k = 4*dq)
        float4 v = *(const float4*)&t2[c][dq * 4];
        *(float4*)&embedT[(size_t)(c0 + c) * DIM + dq * 4] = v;
        ushort4 h;
        h.x = b16rn(-512.0f * v.x); h.y = b16rn(-512.0f * v.y);
        h.z = b16rn(-512.0f * v.z); h.w = b16rn(-512.0f * v.w);
        int C = c0 + c;
        int nb = C >> 7, n = C & 127;
        size_t off = (size_t)nb * 32768 + (size_t)(dq >> 3) * 4096 +
                     (size_t)((dq >> 1) & 3) * 1024 + (size_t)n * 8 + (dq & 1) * 4;
        *(ushort4*)&EbfT[off] = h;
    }
    // e2: 8 threads per code, 32 d each
    {
        int c = tid >> 3, seg = tid & 7;
        float s = 0.f;
        for (int d = seg * 32; d < seg * 32 + 32; ++d)
            s = fmaf(t2[c][d], t2[c][d], s);
        red[c][seg] = s;
    }
    __syncthreads();
    if (tid < 32) {
        float s = 0.f;
        for (int j = 0; j < 8; ++j) s += red[tid][j];
        e2[c0 + tid] = s;
        es2[c0 + tid] = 256.0f * (512.0f + s);
    }
}

// ---------------------------------------------------------------------------
// Screening GEMM: A-fragments register-resident (loaded once), B staged 64 KB
// per barrier pair (1 pair per 128-code tile, 16 total). Per-lane running
// top-2 packed keys key=(u<<13)|idx, u=trunc(256*(512+dist')).
__global__ __launch_bounds__(256, 2) void dist_screen_kernel(
    const unsigned short* __restrict__ Xbf,
    const unsigned short* __restrict__ EbfT,
    const float* __restrict__ es2,
    unsigned int* __restrict__ cand) {
    __shared__ __align__(16) unsigned short Bs[32768];   // 64 KB [kb][quad][n][8]

    const int tid  = threadIdx.x;
    const int lane = tid & 63;
    const int wid  = tid >> 6;
    const int wm   = wid >> 1, wn = wid & 1;
    const int col  = lane & 15, quad = lane >> 4;
    const int nbg  = blockIdx.x;           // 0..3
    const int m0   = blockIdx.y * 128;

    // preload all A fragments: af[mi][kb] (128 VGPRs), reused for 16 n-tiles
    short8 af[4][8];
#pragma unroll
    for (int mi = 0; mi < 4; ++mi) {
        const unsigned short* base =
            Xbf + (size_t)(m0 + wm * 64 + mi * 16 + col) * DIM + quad * 8;
#pragma unroll
        for (int kb = 0; kb < 8; ++kb)
            af[mi][kb] = *(const short8*)(base + kb * 32);
    }

    unsigned b1[16], b2[16];
#pragma unroll
    for (int i = 0; i < 16; ++i) { b1[i] = 0xFFFFFFFFu; b2[i] = 0xFFFFFFFFu; }

    // staging: EbfT tile layout == LDS layout, so src/dst are both contiguous
    const unsigned short* gsrc = EbfT + (size_t)nbg * 16 * 32768 + tid * 8;
    char* ldst = (char*)Bs + tid * 16;

    for (int nt = 0; nt < 16; ++nt) {
        const int n0 = nbg * 2048 + nt * 128;
        __syncthreads();                         // prior tile's reads done
#pragma unroll
        for (int i = 0; i < 16; ++i)
            gl_lds16(gsrc + (size_t)nt * 32768 + i * 2048, ldst + i * 4096);
        __syncthreads();                         // staging complete

        float e_l[4];
#pragma unroll
        for (int ni = 0; ni < 4; ++ni)
            e_l[ni] = es2[n0 + wn * 64 + ni * 16 + col];

#pragma unroll
        for (int nh = 0; nh < 2; ++nh) {         // ni-halves (caps VGPRs)
            floatx4 acc[4][2];
#pragma unroll
            for (int mi = 0; mi < 4; ++mi) {
                acc[mi][0] = (floatx4)0.f; acc[mi][1] = (floatx4)0.f;
            }
            const int n_a = wn * 64 + (nh * 2 + 0) * 16 + col;
            const int n_b = wn * 64 + (nh * 2 + 1) * 16 + col;
#pragma unroll
            for (int kb = 0; kb < 8; ++kb) {
                // bank stride 4 per n -> 2-way aliasing only (free)
                short8 bf0 = *(const short8*)&Bs[kb * 4096 + quad * 1024 + n_a * 8];
                short8 bf1 = *(const short8*)&Bs[kb * 4096 + quad * 1024 + n_b * 8];
#pragma unroll
                for (int mi = 0; mi < 4; ++mi) {
                    acc[mi][0] = __builtin_amdgcn_mfma_f32_16x16x32_bf16(
                        af[mi][kb], bf0, acc[mi][0], 0, 0, 0);
                    acc[mi][1] = __builtin_amdgcn_mfma_f32_16x16x32_bf16(
                        af[mi][kb], bf1, acc[mi][1], 0, 0, 0);
                }
            }
#pragma unroll
            for (int nj = 0; nj < 2; ++nj) {
                int ni = nh * 2 + nj;
                unsigned idxc = (unsigned)(n0 + wn * 64 + ni * 16 + col);
                float e = e_l[ni];
#pragma unroll
                for (int mi = 0; mi < 4; ++mi)
#pragma unroll
                    for (int r = 0; r < 4; ++r) {
                        float d = e + acc[mi][nj][r];
                        unsigned key = ((unsigned)d << 13) + idxc;
                        int s = mi * 4 + r;
                        unsigned lo = umin2(key, b1[s]);
                        unsigned hi = umax2(key, b1[s]);
                        b1[s] = lo;
                        b2[s] = umin2(hi, b2[s]);
                    }
            }
        }
    }

#pragma unroll
    for (int mi = 0; mi < 4; ++mi)
#pragma unroll
        for (int r = 0; r < 4; ++r) {
            int token = m0 + wm * 64 + mi * 16 + quad * 4 + r;
            uint2 v; v.x = b1[mi * 4 + r]; v.y = b2[mi * 4 + r];
            *(uint2*)&cand[(size_t)token * NCAND + nbg * 64 + wn * 32 + col * 2] = v;
        }
}

// ---------------------------------------------------------------------------
// Fused exact fp32 rescore + quantize gather + histogram + embed_sum scatter.
// One wave per token; winner's embedT row kept in registers (bq slice).
__global__ __launch_bounds__(256) void finalize_kernel(
    const float* __restrict__ x, const float* __restrict__ embedT,
    const float* __restrict__ e2,
    const unsigned int* __restrict__ cand,
    float* __restrict__ out, float* __restrict__ esT) {
    __shared__ float partial[4];
    int tid = threadIdx.x, w = tid >> 6, lane = tid & 63;
    int token = blockIdx.x * 4 + w;

    float4 xv = *(const float4*)&x[(size_t)token * DIM + lane * 4];
    float x2 = xv.x * xv.x + xv.y * xv.y + xv.z * xv.z + xv.w * xv.w;
    uint4 c = *(const uint4*)&cand[(size_t)token * NCAND + lane * 4];
    unsigned g = umin2(umin2(c.x, c.y), umin2(c.z, c.w));
#pragma unroll
    for (int m = 1; m < 64; m <<= 1) {
        x2 += __shfl_xor(x2, m);
        g = umin2(g, (unsigned)__shfl_xor((int)g, m));
    }
    const unsigned thr = g + (384u << 13);   // margin 1.5 in true-dist units

    float bd = 3.4e38f; int bk = 0x7fffffff;
    float4 bq = make_float4(0.f, 0.f, 0.f, 0.f);
    unsigned ca[4] = {c.x, c.y, c.z, c.w};
#pragma unroll
    for (int s = 0; s < 4; ++s) {
        unsigned long long mask = __ballot(ca[s] <= thr);
        while (mask) {
            int l = __ffsll(mask) - 1;
            mask &= mask - 1;
            int k = __shfl((int)ca[s], l) & 8191;
            float4 ev = *(const float4*)&embedT[(size_t)k * DIM + lane * 4];
            float p = xv.x * ev.x;
            p = fmaf(xv.y, ev.y, p);
            p = fmaf(xv.z, ev.z, p);
            p = fmaf(xv.w, ev.w, p);
#pragma unroll
            for (int m = 1; m < 64; m <<= 1) p += __shfl_xor(p, m);
            float d = e2[k] - 2.0f * p;
            if (d < bd || (d == bd && k < bk)) { bd = d; bk = k; bq = ev; }
        }
    }
    // outputs: quantize row (per-lane slice of the winner), ind, stats
    *(float4*)&out[OFF_Q + (size_t)token * DIM + lane * 4] = bq;
    float* dst = &esT[(size_t)bk * DIM + lane * 4];
    atomicAdd(dst + 0, xv.x);
    atomicAdd(dst + 1, xv.y);
    atomicAdd(dst + 2, xv.z);
    atomicAdd(dst + 3, xv.w);
    if (lane == 0) {
        out[OFF_IND + token] = (float)bk;
        atomicAdd(&out[OFF_OH + bk], 1.0f);
        partial[w] = x2 + bd;
    }
    __syncthreads();
    if (tid == 0)
        atomicAdd(&out[OFF_DIFF],
                  (partial[0] + partial[1] + partial[2] + partial[3]) *
                  (1.0f / 4194304.0f));
}

// ---------------------------------------------------------------------------
// out[OFF_ES + d*NE + k] = esT[k][d]  (coalesced transpose, writes every cell)
__global__ void es_out_kernel(const float* __restrict__ esT,
                              float* __restrict__ out) {
    __shared__ __align__(16) float t2[32][DIM + 4];
    int k0 = blockIdx.x * 32;
    int tid = threadIdx.x;
    for (int t = 0; t < 8; ++t) {
        int i = t * 256 + tid;          // float4 units over 32x256
        int k = i >> 6, dq = i & 63;
        float4 v = ((const float4*)esT)[(size_t)(k0 + k) * 64 + dq];
        *(float4*)&t2[k][dq * 4] = v;
    }
    __syncthreads();
    for (int t = 0; t < 32; ++t) {
        int i = t * 256 + tid;          // 8192 cells
        int d = i >> 5, c = i & 31;
        out[OFF_ES + (size_t)d * NE + k0 + c] = t2[c][d];
    }
}

// ===========================================================================
extern "C" void kernel_launch(void* const* d_in, const int* in_sizes, int n_in,
                              void* d_out, int out_size, void* d_ws, size_t ws_size,
                              hipStream_t stream) {
    const float* x     = (const float*)d_in[0];
    const float* embed = (const float*)d_in[1];
    float* out = (float*)d_out;

    // ws layout (~46.3 MB; harness ws held >=58 MB in prior rounds)
    char* p = (char*)d_ws;
    unsigned short* Xbf  = (unsigned short*)p;  p += (size_t)NTOK * DIM * 2;    // 8.4 MB
    unsigned short* EbfT = (unsigned short*)p;  p += (size_t)NE * DIM * 2;      // 4.2 MB (tiled)
    float* embedT = (float*)p;                  p += (size_t)NE * DIM * 4;      // 8.4 MB
    float* e2     = (float*)p;                  p += (size_t)NE * 4;
    float* es2    = (float*)p;                  p += (size_t)NE * 4;
    unsigned int* cand = (unsigned int*)p;      p += (size_t)NTOK * NCAND * 4;  // 16.8 MB
    float* esT    = (float*)p;                  p += (size_t)NE * DIM * 4;      // 8.4 MB

    // zero DIFF/IND/OH header (Q/ES fully overwritten) + esT accumulator
    hipMemsetAsync((char*)d_out + (size_t)OFF_DIFF * 4, 0,
                   ((size_t)(OFF_ES - OFF_DIFF)) * 4, stream);
    hipMemsetAsync(esT, 0, (size_t)NE * DIM * 4, stream);

    convert_x_kernel<<<(NTOK * DIM / 4) / 256, 256, 0, stream>>>(x, Xbf);
    convert_e_kernel<<<NE / 32, 256, 0, stream>>>(embed, EbfT, embedT, e2, es2);
    dist_screen_kernel<<<dim3(4, NTOK / 128), 256, 0, stream>>>(
        Xbf, EbfT, es2, cand);
    finalize_kernel<<<NTOK / 4, 256, 0, stream>>>(
        x, embedT, e2, cand, out, esT);
    es_out_kernel<<<NE / 32, 256, 0, stream>>>(esT, out);
}